// Round 1
// 373.320 us; speedup vs baseline: 1.2052x; 1.2052x over previous
//
#include <hip/hip_runtime.h>
#include <math.h>

#define HBINS  4096
#define CAP    4096
#define MAXDET 100

// Order-preserving float -> uint key (larger float => larger key).
static __device__ __forceinline__ unsigned f2key(float f) {
    unsigned u = __float_as_uint(f);
    return (u & 0x80000000u) ? ~u : (u | 0x80000000u);
}

// Pass 1: 4096-bin histogram of score keys (top 12 bits).
__global__ __launch_bounds__(256) void k_hist(const float4* __restrict__ s4, int n4,
                                              unsigned* __restrict__ gh) {
    __shared__ unsigned h[HBINS];
    for (int i = threadIdx.x; i < HBINS; i += 256) h[i] = 0u;
    __syncthreads();
    int stride = gridDim.x * 256;
    for (int i = blockIdx.x * 256 + threadIdx.x; i < n4; i += stride) {
        float4 v = s4[i];
        atomicAdd(&h[f2key(v.x) >> 20], 1u);
        atomicAdd(&h[f2key(v.y) >> 20], 1u);
        atomicAdd(&h[f2key(v.z) >> 20], 1u);
        atomicAdd(&h[f2key(v.w) >> 20], 1u);
    }
    __syncthreads();
    for (int i = threadIdx.x; i < HBINS; i += 256) {
        unsigned c = h[i];
        if (c) atomicAdd(&gh[i], c);
    }
}

// Find highest bin b such that suffix count (all bins >= b) >= MAXDET.
__global__ __launch_bounds__(256) void k_thresh(const unsigned* __restrict__ gh,
                                                unsigned* __restrict__ tkey) {
    __shared__ unsigned buf0[256], buf1[256];
    int t = threadIdx.x;
    unsigned loc[16];
    unsigned s = 0;
#pragma unroll
    for (int i = 0; i < 16; ++i) { loc[i] = gh[t * 16 + i]; s += loc[i]; }
    buf0[t] = s;
    __syncthreads();
    unsigned* src = buf0; unsigned* dst = buf1;
    for (int off = 1; off < 256; off <<= 1) {   // inclusive suffix scan
        unsigned v = src[t];
        if (t + off < 256) v += src[t + off];
        __syncthreads();
        dst[t] = v;
        __syncthreads();
        unsigned* tmp = src; src = dst; dst = tmp;
    }
    unsigned after = (t + 1 < 256) ? src[t + 1] : 0u;  // suffix starting at next thread's range
    if (after < MAXDET && after + s >= MAXDET) {       // crossing is inside my 16 bins
        unsigned run = after;
#pragma unroll
        for (int i = 15; i >= 0; --i) {
            run += loc[i];
            if (run >= MAXDET) { *tkey = ((unsigned)(t * 16 + i)) << 20; break; }
        }
    }
    if (t == 0 && src[0] < MAXDET) *tkey = 0u;  // degenerate fallback: take everything
}

// Pass 2: compact (score, index) of all elements with key >= threshold.
__global__ __launch_bounds__(256) void k_compact(const float4* __restrict__ s4, int n4,
                                                 const unsigned* __restrict__ tkey,
                                                 unsigned* __restrict__ counter,
                                                 float* __restrict__ cs,
                                                 unsigned* __restrict__ ci) {
    unsigned tk = *tkey;
    int stride = gridDim.x * 256;
    for (int i = blockIdx.x * 256 + threadIdx.x; i < n4; i += stride) {
        float4 v = s4[i];
        float f[4] = {v.x, v.y, v.z, v.w};
#pragma unroll
        for (int c = 0; c < 4; ++c) {
            if (f2key(f[c]) >= tk) {
                unsigned p = atomicAdd(counter, 1u);
                if (p < CAP) { cs[p] = f[c]; ci[p] = (unsigned)i * 4u + (unsigned)c; }
            }
        }
    }
}

// Select top-100 in order (bitonic sort), decode boxes, bitmask greedy NMS,
// conf filter, write (100,5).
__global__ __launch_bounds__(256) void k_finalize(const float* __restrict__ rb,
                                                  const float* __restrict__ an,
                                                  const float* __restrict__ cs,
                                                  const unsigned* __restrict__ ci,
                                                  const unsigned* __restrict__ counter,
                                                  float* __restrict__ out) {
    __shared__ unsigned long long comp[CAP];
    __shared__ float bx[MAXDET][4];
    __shared__ float sc[MAXDET];
    __shared__ unsigned long long suppLo[MAXDET];
    __shared__ unsigned long long suppHi[MAXDET];
    __shared__ unsigned long long keepOut[2];

    int t = threadIdx.x;
    unsigned n = *counter;
    if (n > CAP) n = CAP;

    // Composite keys: (score key << 32) | (~idx) => max = best score, tie: lowest idx.
    // This encodes jax.lax.top_k ordering exactly, so descending sort == selection order.
    for (unsigned i = (unsigned)t; i < n; i += 256) {
        comp[i] = ((unsigned long long)f2key(cs[i]) << 32) |
                  (unsigned long long)(0xFFFFFFFFu - ci[i]);
    }
    // Pad to power of two with 0 (sorts to the tail).
    unsigned P = 128;
    while (P < n) P <<= 1;
    for (unsigned i = n + (unsigned)t; i < P; i += 256) comp[i] = 0ull;
    __syncthreads();

    // Bitonic sort, descending. P in [128, 4096]; typical n~150 -> P=256, 36 stages.
    for (unsigned k = 2; k <= P; k <<= 1) {
        for (unsigned j = k >> 1; j > 0; j >>= 1) {
            for (unsigned i = (unsigned)t; i < P; i += 256) {
                unsigned l = i ^ j;
                if (l > i) {
                    unsigned long long a = comp[i], b = comp[l];
                    bool up = ((i & k) == 0);          // descending network
                    if (up ? (a < b) : (a > b)) { comp[i] = b; comp[l] = a; }
                }
            }
            __syncthreads();
        }
    }

    // Decode the 100 selected boxes (reference math, fp32) + init supp masks.
    if (t < MAXDET) {
        unsigned long long gb = comp[t];
        float raw;
        unsigned id;
        if (gb == 0ull) {                 // fewer than 100 candidates (pathological)
            raw = -3.0e38f;
            id = 0u;
        } else {
            unsigned key = (unsigned)(gb >> 32);
            unsigned u = (key & 0x80000000u) ? (key & 0x7FFFFFFFu) : ~key;
            raw = __uint_as_float(u);
            id = 0xFFFFFFFFu - (unsigned)(gb & 0xFFFFFFFFull);
        }
        size_t b = (size_t)id * 16;
        float rb0 = rb[b + 0], rb1 = rb[b + 1], rb2 = rb[b + 2], rb3 = rb[b + 3];
        size_t a = (size_t)id * 4;
        float ax = an[a + 0], ay = an[a + 1], aw = an[a + 2], ah = an[a + 3];
        const float inv = 1.0f / 128.0f;   // INPUT_SIZE, exact power of two
        float xc = rb0 * inv * aw + ax;
        float yc = rb1 * inv * ah + ay;
        float w  = rb2 * inv * aw;
        float h  = rb3 * inv * ah;
        float y0 = yc - h * 0.5f, y1 = yc + h * 0.5f;
        float x0 = xc - w * 0.5f, x1 = xc + w * 0.5f;
        bx[t][0] = fminf(y0, y1);
        bx[t][1] = fminf(x0, x1);
        bx[t][2] = fmaxf(y0, y1);
        bx[t][3] = fmaxf(x0, x1);
        float r = fminf(fmaxf(raw, -100.0f), 100.0f);
        sc[t] = 1.0f / (1.0f + expf(-r));
        suppLo[t] = 0ull;
        suppHi[t] = 0ull;
    }
    __syncthreads();

    // Parallel IoU: all (i,j) j>i pairs -> suppression bitmasks (bit j of supp[i]).
    for (int p = t; p < MAXDET * MAXDET; p += 256) {
        int i = p / MAXDET, j = p - i * MAXDET;
        if (j > i) {
            float x1i = bx[i][1], y1i = bx[i][0], x2i = bx[i][3], y2i = bx[i][2];
            float x1j = bx[j][1], y1j = bx[j][0], x2j = bx[j][3], y2j = bx[j][2];
            float areai = (x2i - x1i) * (y2i - y1i);
            float areaj = (x2j - x1j) * (y2j - y1j);
            float xx1 = fmaxf(x1i, x1j), yy1 = fmaxf(y1i, y1j);
            float xx2 = fminf(x2i, x2j), yy2 = fminf(y2i, y2j);
            float iw = fmaxf(xx2 - xx1, 0.0f), ih = fmaxf(yy2 - yy1, 0.0f);
            float inter = iw * ih;
            float uni = areai + areaj - inter;
            float iou = inter / fmaxf(uni, 1e-9f);
            if (iou > 0.3f) {
                if (j < 64) atomicOr(&suppLo[i], 1ull << j);
                else        atomicOr(&suppHi[i], 1ull << (j - 64));
            }
        }
    }
    __syncthreads();

    // Sequential greedy resolve on register-resident masks (wave 0, all lanes uniform).
    // Exactly the reference fori_loop: supp applied only if i still kept at time i.
    if (t < 64) {
        unsigned long long a0 = suppLo[t], a1 = suppHi[t];
        unsigned long long b0 = (t < MAXDET - 64) ? suppLo[64 + t] : 0ull;
        unsigned long long b1 = (t < MAXDET - 64) ? suppHi[64 + t] : 0ull;
        unsigned long long kLo = ~0ull;
        unsigned long long kHi = (1ull << (MAXDET - 64)) - 1;
        for (int i = 0; i < MAXDET - 1; ++i) {
            bool kept = (i < 64) ? ((kLo >> i) & 1ull) : ((kHi >> (i - 64)) & 1ull);
            if (kept) {                                  // uniform across lanes
                unsigned long long mLo = (i < 64) ? __shfl(a0, i) : __shfl(b0, i - 64);
                unsigned long long mHi = (i < 64) ? __shfl(a1, i) : __shfl(b1, i - 64);
                kLo &= ~mLo;
                kHi &= ~mHi;
            }
        }
        if (t == 0) { keepOut[0] = kLo; keepOut[1] = kHi; }
    }
    __syncthreads();

    // Confidence mask + write (100, 5): [ymin, xmin, ymax, xmax, score] or zeros.
    if (t < MAXDET) {
        unsigned long long km = (t < 64) ? keepOut[0] : keepOut[1];
        bool kb = (km >> (t & 63)) & 1ull;
        bool k = kb && (sc[t] >= 0.75f);
        float* o = out + t * 5;
        o[0] = k ? bx[t][0] : 0.0f;
        o[1] = k ? bx[t][1] : 0.0f;
        o[2] = k ? bx[t][2] : 0.0f;
        o[3] = k ? bx[t][3] : 0.0f;
        o[4] = k ? sc[t]    : 0.0f;
    }
}

extern "C" void kernel_launch(void* const* d_in, const int* in_sizes, int n_in,
                              void* d_out, int out_size, void* d_ws, size_t ws_size,
                              hipStream_t stream) {
    const float* raw_boxes  = (const float*)d_in[0];   // (1, N, 16)
    const float* raw_scores = (const float*)d_in[1];   // (1, N, 1)
    const float* anchors    = (const float*)d_in[2];   // (N, 4)
    float* out = (float*)d_out;                        // (100, 5)

    int n_scores = in_sizes[1];
    int n4 = n_scores / 4;

    // Workspace layout (bytes):
    //   [0, 16384)      unsigned hist[4096]
    //   [16384, 16388)  unsigned counter
    //   [16388, 16392)  unsigned thresh_key
    //   [16400, 32784)  float    cand_score[CAP]
    //   [32784, 49168)  unsigned cand_idx[CAP]
    unsigned* gh      = (unsigned*)d_ws;
    unsigned* counter = gh + HBINS;
    unsigned* tkey    = counter + 1;
    float*    cs      = (float*)((char*)d_ws + 16400);
    unsigned* ci      = (unsigned*)(cs + CAP);

    hipMemsetAsync(d_ws, 0, 16400, stream);  // zero hist + counter (+ tkey)

    k_hist<<<512, 256, 0, stream>>>((const float4*)raw_scores, n4, gh);
    k_thresh<<<1, 256, 0, stream>>>(gh, tkey);
    k_compact<<<4096, 256, 0, stream>>>((const float4*)raw_scores, n4, tkey, counter, cs, ci);
    k_finalize<<<1, 256, 0, stream>>>(raw_boxes, anchors, cs, ci, counter, out);
}